// Round 7
// baseline (291.107 us; speedup 1.0000x reference)
//
#include <hip/hip_runtime.h>

#define HWSZ (512 * 512)
#define NCH 32
#define WSTRIDE 292          // padded stride (292 % 32 == 4 -> leaves spread over 8 bank groups)
#define NW (64 * WSTRIDE)    // 18688 floats = 74752 B
#define WS_WALL_OFF 128      // ws[0..53]=norm split wts, ws[64..127]=b_all, ws[128..]=w_all
#define THRESH 0.4054651081081644f  // ln(1.5): sigmoid(v)<0.6  <=>  v<ln(1.5)

// ---------------- prep: build fused weight table in workspace ----------------
__global__ void prep_kernel(const float* __restrict__ w_split,
                            const float* __restrict__ w_pred,
                            const float* __restrict__ b_pred,
                            float* __restrict__ ws) {
  const int tid = threadIdx.x;
  const int blk = blockIdx.x;
  if (blk < 64) {
    if (tid < 288) {
      const int c = tid / 9, t = tid % 9;
      float s = 0.f;
      #pragma unroll 8
      for (int l = 0; l < 64; ++l) s += w_pred[l * 288 + tid];
      s *= (1.0f / 64.0f);
      ws[WS_WALL_OFF + blk * WSTRIDE + t * 32 + c] = w_pred[blk * 288 + tid] + s;
    }
    if (tid >= 288 && tid < 292) {
      ws[WS_WALL_OFF + blk * WSTRIDE + tid] = 0.f;
    }
  } else {
    if (tid < 6) {
      float w[9];
      float s = 0.f;
      #pragma unroll
      for (int e = 0; e < 9; ++e) {
        float v = fmaxf(w_split[tid * 9 + e], 0.f);
        w[e] = v;
        s += v;
      }
      const float add = (s < 0.1f) ? (0.1f / 9.0f) : 0.0f;
      #pragma unroll
      for (int e = 0; e < 9; ++e) ws[tid * 9 + e] = w[e] + add;
    }
    if (tid >= 64 && tid < 128) {
      float s = 0.f;
      #pragma unroll 8
      for (int j = 0; j < 64; ++j) s += b_pred[j];
      ws[64 + (tid - 64)] = b_pred[tid - 64] + s * (1.0f / 64.0f);
    }
  }
}

// ---------------- main ----------------
// Block: 1024 threads = 16 waves; wave = one row of 128 px (64 lanes x 2 px).
// Block tile: 128 wide x 16 rows. Grid (4, 32, 4) = 512 blocks = 2 blocks/CU.
// LDS: fused weight table 75 KB -> 2 blocks/CU = 150 KB, 8 waves/SIMD.
// NO cross-lane shuffles: each lane loads its 4-wide window directly
// (float2 @xx0 + dword @xx0-1 + dword @xx0+2) so data VMEM and weight DS
// streams are independent and can both be pipelined by the compiler.
__global__ __launch_bounds__(1024, 8) void main_kernel(
    const float* __restrict__ x, const float* __restrict__ data,
    const float* __restrict__ ws, float* __restrict__ out) {
  __shared__ float s_w[NW + 64];

  const int tid = threadIdx.x;

  // ---- issue LDS fill first; it overlaps the split-leaf computation ----
  {
    const float4* __restrict__ src = (const float4*)(ws + WS_WALL_OFF);
    float4* dst = (float4*)s_w;
    #pragma unroll 1
    for (int i = tid; i < NW / 4; i += 1024) dst[i] = src[i];
    if (tid < 64) s_w[NW + tid] = ws[64 + tid];
  }

  const int lane = tid & 63;
  const int wvid = tid >> 6;   // 0..15
  const int bx = blockIdx.x;   // 0..3
  const int by = blockIdx.y;   // 0..31
  const int n = blockIdx.z;    // 0..3
  const int xx0 = bx * 128 + lane * 2;
  const int yy = by * 16 + wvid;

  const int offL = max(xx0 - 1, 0);      // left tap of px0
  const int offR = min(xx0 + 2, 511);    // right tap of px1
  const float lm = (xx0 > 0) ? 1.f : 0.f;
  const float rm = (xx0 < 510) ? 1.f : 0.f;

  // ---------- split-tree leaves for the 2 pixels ----------
  const float* xim = x + (size_t)n * HWSZ;
  float xwin[3][4];  // [dy][{left, p0, p1, right}]
  #pragma unroll
  for (int dy = 0; dy < 3; ++dy) {
    const int ry = yy + dy - 1;
    if ((unsigned)ry < 512u) {
      const float* rp = xim + ry * 512;
      const float2 m2 = *(const float2*)(rp + xx0);
      xwin[dy][0] = rp[offL] * lm;
      xwin[dy][1] = m2.x;
      xwin[dy][2] = m2.y;
      xwin[dy][3] = rp[offR] * rm;
    } else {
      xwin[dy][0] = xwin[dy][1] = xwin[dy][2] = xwin[dy][3] = 0.f;
    }
  }
  int lf0 = 0, lf1 = 0;
  #pragma unroll
  for (int f = 0; f < 6; ++f) {
    float v0 = 0.f, v1 = 0.f;
    #pragma unroll
    for (int dy = 0; dy < 3; ++dy) {
      #pragma unroll
      for (int dx = 0; dx < 3; ++dx) {
        const float wv = ws[f * 9 + dy * 3 + dx];
        v0 = fmaf(xwin[dy][dx], wv, v0);
        v1 = fmaf(xwin[dy][dx + 1], wv, v1);
      }
    }
    const int bit = 32 >> f;  // filter 0 is the MSB
    if (v0 < THRESH) lf0 |= bit;
    if (v1 < THRESH) lf1 |= bit;
  }

  __syncthreads();  // weight table ready

  // ---------- fused (base + selected) conv; weights from LDS ----------
  const float* wl0 = s_w + lf0 * WSTRIDE;
  const float* wl1 = s_w + lf1 * WSTRIDE;
  const float* dbase = data + (size_t)n * NCH * HWSZ;

  float4 acc0 = make_float4(0.f, 0.f, 0.f, 0.f);
  float4 acc1 = make_float4(0.f, 0.f, 0.f, 0.f);

  #pragma unroll 1
  for (int cg = 0; cg < 8; ++cg) {
    const float* ch0 = dbase + (size_t)cg * 4 * HWSZ;
    #pragma unroll
    for (int dy = 0; dy < 3; ++dy) {
      const int ry = yy + dy - 1;
      if ((unsigned)ry < 512u) {
        const float* r0 = ch0 + ry * 512;
        const float* r1 = r0 + HWSZ;
        const float* r2 = r1 + HWSZ;
        const float* r3 = r2 + HWSZ;
        // ---- all 12 data loads of this iteration, no cross-lane deps ----
        const float2 ma = *(const float2*)(r0 + xx0);
        const float2 mb = *(const float2*)(r1 + xx0);
        const float2 mc = *(const float2*)(r2 + xx0);
        const float2 md = *(const float2*)(r3 + xx0);
        const float la = r0[offL] * lm, ra = r0[offR] * rm;
        const float lb = r1[offL] * lm, rb = r1[offR] * rm;
        const float lc = r2[offL] * lm, rc = r2[offR] * rm;
        const float ld = r3[offL] * lm, rd = r3[offR] * rm;

        const int tbase = dy * 3 * 32 + cg * 4;
        // dx = 0: px0 uses left, px1 uses p0
        {
          const float4 w0 = *(const float4*)(wl0 + tbase);
          const float4 w1 = *(const float4*)(wl1 + tbase);
          acc0.x = fmaf(la, w0.x, acc0.x); acc1.x = fmaf(ma.x, w1.x, acc1.x);
          acc0.y = fmaf(lb, w0.y, acc0.y); acc1.y = fmaf(mb.x, w1.y, acc1.y);
          acc0.z = fmaf(lc, w0.z, acc0.z); acc1.z = fmaf(mc.x, w1.z, acc1.z);
          acc0.w = fmaf(ld, w0.w, acc0.w); acc1.w = fmaf(md.x, w1.w, acc1.w);
        }
        // dx = 1: px0 uses p0, px1 uses p1
        {
          const float4 w0 = *(const float4*)(wl0 + tbase + 32);
          const float4 w1 = *(const float4*)(wl1 + tbase + 32);
          acc0.x = fmaf(ma.x, w0.x, acc0.x); acc1.x = fmaf(ma.y, w1.x, acc1.x);
          acc0.y = fmaf(mb.x, w0.y, acc0.y); acc1.y = fmaf(mb.y, w1.y, acc1.y);
          acc0.z = fmaf(mc.x, w0.z, acc0.z); acc1.z = fmaf(mc.y, w1.z, acc1.z);
          acc0.w = fmaf(md.x, w0.w, acc0.w); acc1.w = fmaf(md.y, w1.w, acc1.w);
        }
        // dx = 2: px0 uses p1, px1 uses right
        {
          const float4 w0 = *(const float4*)(wl0 + tbase + 64);
          const float4 w1 = *(const float4*)(wl1 + tbase + 64);
          acc0.x = fmaf(ma.y, w0.x, acc0.x); acc1.x = fmaf(ra, w1.x, acc1.x);
          acc0.y = fmaf(mb.y, w0.y, acc0.y); acc1.y = fmaf(rb, w1.y, acc1.y);
          acc0.z = fmaf(mc.y, w0.z, acc0.z); acc1.z = fmaf(rc, w1.z, acc1.z);
          acc0.w = fmaf(md.y, w0.w, acc0.w); acc1.w = fmaf(rd, w1.w, acc1.w);
        }
      }
    }
  }

  const float res0 = acc0.x + acc0.y + acc0.z + acc0.w + s_w[NW + lf0];
  const float res1 = acc1.x + acc1.y + acc1.z + acc1.w + s_w[NW + lf1];
  *(float2*)(out + (size_t)n * HWSZ + yy * 512 + xx0) = make_float2(res0, res1);
}

extern "C" void kernel_launch(void* const* d_in, const int* in_sizes, int n_in,
                              void* d_out, int out_size, void* d_ws,
                              size_t ws_size, hipStream_t stream) {
  const float* x = (const float*)d_in[0];        // [4,1,512,512]
  const float* data = (const float*)d_in[1];     // [4,32,512,512]
  const float* w_split = (const float*)d_in[2];  // [6,1,3,3]
  const float* w_pred = (const float*)d_in[3];   // [64,32,3,3]
  const float* b_pred = (const float*)d_in[4];   // [64]
  float* out = (float*)d_out;                    // [4,512,512]
  float* ws = (float*)d_ws;                      // 128 + 64*292 floats (~74 KB)

  prep_kernel<<<65, 320, 0, stream>>>(w_split, w_pred, b_pred, ws);
  main_kernel<<<dim3(4, 32, 4), 1024, 0, stream>>>(x, data, ws, out);
}